// Round 5
// baseline (421.447 us; speedup 1.0000x reference)
//
#include <hip/hip_runtime.h>
#include <math.h>

#define B_ 256
#define L_ 256
#define V_ 2048
#define DIN_ 128
#define H_ 256
#define NODES_ 511

typedef _Float16 half8 __attribute__((ext_vector_type(8)));
typedef float f32x4 __attribute__((ext_vector_type(4)));

__device__ __forceinline__ float sigm(float x) { return 1.f / (1.f + __expf(-x)); }
__device__ __forceinline__ float tanh_f(float x) {
    float xc = fminf(fmaxf(x, -15.f), 15.f);
    float e = __expf(2.f * xc);
    return (e - 1.f) / (e + 1.f);
}
__device__ __forceinline__ void gload16(const void* g, void* l) {
    __builtin_amdgcn_global_load_lds((const __attribute__((address_space(1))) unsigned int*)g,
                                     (__attribute__((address_space(3))) unsigned int*)l, 16, 0, 0);
}

// WTh[n][k] fp16: h-part weights only. n = g*256+t (g:0=i,1=o,2=u,3=f0,4=f1), k:[0,256)=h1,[256,512)=h2
__global__ void build_WTh(_Float16* __restrict__ WTh,
    const float* __restrict__ Wiouh1, const float* __restrict__ Wfh11, const float* __restrict__ Wfh21,
    const float* __restrict__ Wiouh2, const float* __restrict__ Wfh12, const float* __restrict__ Wfh22)
{
    int e = blockIdx.x * 256 + threadIdx.x;   // < 1280*512
    int nn = e >> 9, k = e & 511;
    int g = nn >> 8, t = nn & 255;
    float v;
    if (k < 256) {
        v = (g < 3) ? Wiouh1[k * 768 + nn] : ((g == 3) ? Wfh11[k * 256 + t] : Wfh21[k * 256 + t]);
    } else {
        int kp = k - 256;
        v = (g < 3) ? Wiouh2[kp * 768 + nn] : ((g == 3) ? Wfh12[kp * 256 + t] : Wfh22[kp * 256 + t]);
    }
    WTh[e] = (_Float16)v;
}

// tab[id][col] f32 = emb(id,:) @ Wx_fused(:,col) + bias_total(col); emb row 0 zeroed.
__global__ __launch_bounds__(256) void build_table(float* __restrict__ tab, const float* __restrict__ emb,
    const float* __restrict__ Wioux, const float* __restrict__ Wfx,
    const float* __restrict__ bioux, const float* __restrict__ biouh1, const float* __restrict__ biouh2,
    const float* __restrict__ bfx, const float* __restrict__ bfh11, const float* __restrict__ bfh12,
    const float* __restrict__ bfh21, const float* __restrict__ bfh22)
{
    __shared__ float As[64][33];
    __shared__ float Ws[32][65];
    const int tid = threadIdx.x, tx = tid & 15, ty = tid >> 4;
    const int i0 = blockIdx.x * 64, c0 = blockIdx.y * 64;
    const int g = c0 >> 8;
    float acc[4][4];
    #pragma unroll
    for (int i = 0; i < 4; ++i)
        #pragma unroll
        for (int j = 0; j < 4; ++j) acc[i][j] = 0.f;

    for (int k0 = 0; k0 < 128; k0 += 32) {
        #pragma unroll
        for (int it = 0; it < 2; ++it) {
            int f = tid + it * 256;
            int row = f >> 3, kk = (f & 7) * 4;
            int gr = i0 + row;
            float4 av = (gr == 0) ? make_float4(0.f, 0.f, 0.f, 0.f)
                                  : *(const float4*)(emb + (size_t)gr * 128 + k0 + kk);
            As[row][kk] = av.x; As[row][kk + 1] = av.y; As[row][kk + 2] = av.z; As[row][kk + 3] = av.w;
            int k = f >> 4, cc = (f & 15) * 4;
            int col = c0 + cc;
            float4 wv = (g < 3) ? *(const float4*)(Wioux + (size_t)(k0 + k) * 768 + col)
                                : *(const float4*)(Wfx + (size_t)(k0 + k) * 256 + (col & 255));
            Ws[k][cc] = wv.x; Ws[k][cc + 1] = wv.y; Ws[k][cc + 2] = wv.z; Ws[k][cc + 3] = wv.w;
        }
        __syncthreads();
        #pragma unroll 8
        for (int k = 0; k < 32; ++k) {
            float a[4], w[4];
            #pragma unroll
            for (int i = 0; i < 4; ++i) a[i] = As[ty * 4 + i][k];
            #pragma unroll
            for (int j = 0; j < 4; ++j) w[j] = Ws[k][tx * 4 + j];
            #pragma unroll
            for (int i = 0; i < 4; ++i)
                #pragma unroll
                for (int j = 0; j < 4; ++j) acc[i][j] = fmaf(a[i], w[j], acc[i][j]);
        }
        __syncthreads();
    }
    #pragma unroll
    for (int j = 0; j < 4; ++j) {
        int col = c0 + tx * 4 + j; int t = col & 255;
        float bs = (g < 3) ? (bioux[col] + biouh1[col] + biouh2[col])
                 : (g == 3) ? (bfx[t] + bfh11[t] + bfh12[t])
                            : (bfx[t] + bfh21[t] + bfh22[t]);
        #pragma unroll
        for (int i = 0; i < 4; ++i)
            tab[(size_t)(i0 + ty * 4 + i) * 1280 + col] = acc[i][j] + bs;
    }
}

// Level-0 result depends only on token id: H0h/H0c[id][t]
__global__ void build_h0c0(const float* __restrict__ tab, _Float16* __restrict__ H0h, float* __restrict__ H0c) {
    int id = blockIdx.x, t = threadIdx.x;
    const float* tp = tab + (size_t)id * 1280 + t;
    float vi = sigm(tp[0]), vo = sigm(tp[256]), vu = tanh_f(tp[512]);
    float c = vi * vu;
    H0h[id * 256 + t] = (_Float16)(vo * tanh_f(c));
    H0c[id * 256 + t] = c;
}

// Tree-level cell v4: BM=256 rows (4 waves x 64) x 32 t-cols x 5 gates (BN=160). K=512, BK=32.
// Per wave-step: 40 MFMA vs 10 ds_read_b128 (B) + 4 direct A-loads.
// B: LDS double-buffered via global_load_lds; seg-swizzle s(n)=(n>>1)&3 (2-way = free).
// A: direct per-lane global loads (fragment layout), depth-1 register prefetch.
template<bool LVL1>
__global__ __launch_bounds__(256, 2) void cell4(
    const _Float16* __restrict__ WTh, const float* __restrict__ tab,
    const int* __restrict__ ids,
    const _Float16* __restrict__ h_prev, const float* __restrict__ c_prev,
    _Float16* __restrict__ h_out, float* __restrict__ c_out,
    int n, int ln, int off)
{
    __shared__ _Float16 Bs[2][160 * 32];       // 10KB per buffer
    const int tid = threadIdx.x, lane = tid & 63, wid = tid >> 6;
    const int l15 = lane & 15, lg = lane >> 4;
    const int rowB = blockIdx.x * 256;
    const int t0 = blockIdx.y * 32;

    // ---- A source pointers per row-frag (k<256 -> aPA, k>=256 -> aPB)
    const _Float16* aPA[4];
    const _Float16* aPB[4];
    #pragma unroll
    for (int rt = 0; rt < 4; ++rt) {
        int row = rowB + wid * 64 + rt * 16 + l15;
        if constexpr (LVL1) {
            int b = row >> 7, j = row & 127;
            aPA[rt] = h_prev + (size_t)ids[b * NODES_ + 2 * j] * 256 + lg * 8;
            aPB[rt] = h_prev + (size_t)ids[b * NODES_ + 2 * j + 1] * 256 + lg * 8;
        } else {
            aPA[rt] = h_prev + (size_t)row * 512 + lg * 8;
            aPB[rt] = aPA[rt] + 256;
        }
    }

    // ---- B staging sources (seg pre-swizzled: slot j of row nb holds seg j^((nb>>1)&3))
    const _Float16* srcB[3];
    #pragma unroll
    for (int q = 0; q < 3; ++q) {
        int f = q * 256 + tid;                 // 16B slot, < 640 (q=2 valid when tid<128)
        int nb = f >> 2, j = f & 3;
        int g = nb >> 5, tl = nb & 31;
        srcB[q] = WTh + (size_t)(g * 256 + t0 + tl) * 512 + ((j ^ ((nb >> 1) & 3)) * 8);
    }

    f32x4 acc[4][10];                          // [row-frag][gate*2+thalf]
    #pragma unroll
    for (int rt = 0; rt < 4; ++rt)
        #pragma unroll
        for (int c = 0; c < 10; ++c) acc[rt][c] = (f32x4)0.f;

    half8 aF[2][4];
    // prologue: stage B(0), load A(0)
    gload16(srcB[0], &Bs[0][(size_t)tid * 8]);
    gload16(srcB[1], &Bs[0][(size_t)(256 + tid) * 8]);
    if (tid < 128) gload16(srcB[2], &Bs[0][(size_t)(512 + tid) * 8]);
    #pragma unroll
    for (int rt = 0; rt < 4; ++rt) aF[0][rt] = *(const half8*)(aPA[rt]);
    __syncthreads();

    #pragma unroll
    for (int s = 0; s < 16; ++s) {
        const int cur = s & 1, nxt = cur ^ 1;
        if (s < 15) {
            const int k1 = (s + 1) * 32;
            gload16(srcB[0] + k1, &Bs[nxt][(size_t)tid * 8]);
            gload16(srcB[1] + k1, &Bs[nxt][(size_t)(256 + tid) * 8]);
            if (tid < 128) gload16(srcB[2] + k1, &Bs[nxt][(size_t)(512 + tid) * 8]);
            #pragma unroll
            for (int rt = 0; rt < 4; ++rt)
                aF[nxt][rt] = (k1 < 256) ? *(const half8*)(aPA[rt] + k1)
                                         : *(const half8*)(aPB[rt] + (k1 - 256));
        }
        #pragma unroll
        for (int g = 0; g < 5; ++g)
            #pragma unroll
            for (int th = 0; th < 2; ++th) {
                int nb = g * 32 + th * 16 + l15;
                half8 bF = *(const half8*)&Bs[cur][nb * 32 + ((lg ^ ((nb >> 1) & 3)) * 8)];
                #pragma unroll
                for (int rt = 0; rt < 4; ++rt)
                    acc[rt][g * 2 + th] = __builtin_amdgcn_mfma_f32_16x16x32_f16(aF[cur][rt], bF, acc[rt][g * 2 + th], 0, 0, 0);
            }
        __syncthreads();
    }

    // ---- fused epilogue. D: col = lane&15, row = (lane>>4)*4 + q
    #pragma unroll
    for (int rt = 0; rt < 4; ++rt) {
        #pragma unroll
        for (int q = 0; q < 4; ++q) {
            int row = rowB + wid * 64 + rt * 16 + lg * 4 + q;
            int b = row >> ln, j = row & (n - 1);
            int id = ids[b * NODES_ + off + j];
            #pragma unroll
            for (int th = 0; th < 2; ++th) {
                int tcol = t0 + th * 16 + l15;
                const float* tp = tab + (size_t)id * 1280 + tcol;
                float c1, c2;
                if constexpr (LVL1) {
                    int bb = row >> 7, jj = row & 127;
                    c1 = c_prev[(size_t)ids[bb * NODES_ + 2 * jj] * 256 + tcol];
                    c2 = c_prev[(size_t)ids[bb * NODES_ + 2 * jj + 1] * 256 + tcol];
                } else {
                    const float* cpp = c_prev + (size_t)row * 512 + tcol;
                    c1 = cpp[0]; c2 = cpp[256];
                }
                float vi  = sigm(acc[rt][0 + th][q] + tp[0]);
                float vo  = sigm(acc[rt][2 + th][q] + tp[256]);
                float vu  = tanh_f(acc[rt][4 + th][q] + tp[512]);
                float vf0 = sigm(acc[rt][6 + th][q] + tp[768]);
                float vf1 = sigm(acc[rt][8 + th][q] + tp[1024]);
                float c = vi * vu + vf0 * c1 + vf1 * c2;
                size_t ob = (size_t)row * 256 + tcol;
                h_out[ob] = (_Float16)(vo * tanh_f(c));
                c_out[ob] = c;
            }
        }
    }
}

// pred[b] = relu(h_root[b] @ Wl1 + bl1) @ Wl2 + bl2
__global__ void head_kernel(const _Float16* __restrict__ hroot,
    const float* __restrict__ Wl1, const float* __restrict__ bl1,
    const float* __restrict__ Wl2, const float* __restrict__ bl2,
    float* __restrict__ out)
{
    __shared__ float hrow[H_];
    __shared__ float red[256];
    int b = blockIdx.x; int tid = threadIdx.x;
    hrow[tid] = (float)hroot[(size_t)b * H_ + tid];
    __syncthreads();
    float v = 0.f;
    if (tid < 100) {
        float s = bl1[tid];
        for (int k = 0; k < H_; ++k) s = fmaf(hrow[k], Wl1[k * 100 + tid], s);
        v = fmaxf(s, 0.f) * Wl2[tid];
    }
    red[tid] = v;
    __syncthreads();
    for (int s = 128; s > 0; s >>= 1) { if (tid < s) red[tid] += red[tid + s]; __syncthreads(); }
    if (tid == 0) out[b] = red[0] + bl2[0];
}

extern "C" void kernel_launch(void* const* d_in, const int* in_sizes, int n_in,
                              void* d_out, int out_size, void* d_ws, size_t ws_size,
                              hipStream_t stream) {
    const int*   ids    = (const int*)d_in[0];
    const float* emb    = (const float*)d_in[1];
    const float* Wioux  = (const float*)d_in[2];
    const float* bioux  = (const float*)d_in[3];
    const float* Wiouh1 = (const float*)d_in[4];
    const float* biouh1 = (const float*)d_in[5];
    const float* Wiouh2 = (const float*)d_in[6];
    const float* biouh2 = (const float*)d_in[7];
    const float* Wfx    = (const float*)d_in[8];
    const float* bfx    = (const float*)d_in[9];
    const float* Wfh11  = (const float*)d_in[10];
    const float* bfh11  = (const float*)d_in[11];
    const float* Wfh12  = (const float*)d_in[12];
    const float* bfh12  = (const float*)d_in[13];
    const float* Wfh21  = (const float*)d_in[14];
    const float* bfh21  = (const float*)d_in[15];
    const float* Wfh22  = (const float*)d_in[16];
    const float* bfh22  = (const float*)d_in[17];
    const float* Wl1    = (const float*)d_in[18];
    const float* bl1    = (const float*)d_in[19];
    const float* Wl2    = (const float*)d_in[20];
    const float* bl2    = (const float*)d_in[21];
    float* out = (float*)d_out;

    // ws layout (bytes)
    char* wsb = (char*)d_ws;
    _Float16* WTh = (_Float16*)(wsb);                    //  1,310,720
    float*    tab = (float*)(wsb + 1310720);             // 10,485,760
    _Float16* H0h = (_Float16*)(wsb + 11796480);         //  1,048,576
    float*    H0c = (float*)(wsb + 12845056);            //  2,097,152
    _Float16* hA  = (_Float16*)(wsb + 14942208);         //  8,388,608  (lvl 2,4,6,8 out)
    _Float16* hB  = (_Float16*)(wsb + 23330816);         // 16,777,216  (lvl 1,3,5,7 out)
    float*    cA  = (float*)(wsb + 40108032);            // 16,777,216
    float*    cB  = (float*)(wsb + 56885248);            // 33,554,432  -> ends 90,439,680

    build_WTh<<<dim3(2560), 256, 0, stream>>>(WTh, Wiouh1, Wfh11, Wfh21, Wiouh2, Wfh12, Wfh22);
    build_table<<<dim3(32, 20), 256, 0, stream>>>(tab, emb, Wioux, Wfx,
        bioux, biouh1, biouh2, bfx, bfh11, bfh12, bfh21, bfh22);
    build_h0c0<<<dim3(2048), 256, 0, stream>>>(tab, H0h, H0c);

    // level 1: A gathered from id-indexed H0 tables
    cell4<true><<<dim3(128, 8), 256, 0, stream>>>(WTh, tab, ids, H0h, H0c, hB, cB, 128, 7, 256);

    _Float16 *hp = hB, *hn = hA;
    float    *cp = cB, *cn = cA;
    int off = 384, n = 64, ln = 6;
    for (int lvl = 2; lvl <= 8; ++lvl) {
        int M = B_ * n;
        cell4<false><<<dim3(M / 256, 8), 256, 0, stream>>>(WTh, tab, ids, hp, cp, hn, cn, n, ln, off);
        off += n; n >>= 1; --ln;
        _Float16* t1 = hp; hp = hn; hn = t1;
        float*    t2 = cp; cp = cn; cn = t2;
    }

    head_kernel<<<dim3(256), 256, 0, stream>>>(hp, Wl1, bl1, Wl2, bl2, out);
}

// Round 6
// 293.175 us; speedup vs baseline: 1.4375x; 1.4375x over previous
//
#include <hip/hip_runtime.h>
#include <math.h>

#define B_ 256
#define L_ 256
#define V_ 2048
#define DIN_ 128
#define H_ 256
#define NODES_ 511

typedef _Float16 half8 __attribute__((ext_vector_type(8)));
typedef float f32x4 __attribute__((ext_vector_type(4)));

__device__ __forceinline__ float sigm(float x) { return 1.f / (1.f + __expf(-x)); }
__device__ __forceinline__ float tanh_f(float x) {
    float xc = fminf(fmaxf(x, -15.f), 15.f);
    float e = __expf(2.f * xc);
    return (e - 1.f) / (e + 1.f);
}
__device__ __forceinline__ void gload16(const void* g, void* l) {
    __builtin_amdgcn_global_load_lds((const __attribute__((address_space(1))) unsigned int*)g,
                                     (__attribute__((address_space(3))) unsigned int*)l, 16, 0, 0);
}

// WTh[n][k] fp16: h-part weights only. n = g*256+t (g:0=i,1=o,2=u,3=f0,4=f1), k:[0,256)=h1,[256,512)=h2
__global__ void build_WTh(_Float16* __restrict__ WTh,
    const float* __restrict__ Wiouh1, const float* __restrict__ Wfh11, const float* __restrict__ Wfh21,
    const float* __restrict__ Wiouh2, const float* __restrict__ Wfh12, const float* __restrict__ Wfh22)
{
    int e = blockIdx.x * 256 + threadIdx.x;   // < 1280*512
    int nn = e >> 9, k = e & 511;
    int g = nn >> 8, t = nn & 255;
    float v;
    if (k < 256) {
        v = (g < 3) ? Wiouh1[k * 768 + nn] : ((g == 3) ? Wfh11[k * 256 + t] : Wfh21[k * 256 + t]);
    } else {
        int kp = k - 256;
        v = (g < 3) ? Wiouh2[kp * 768 + nn] : ((g == 3) ? Wfh12[kp * 256 + t] : Wfh22[kp * 256 + t]);
    }
    WTh[e] = (_Float16)v;
}

// tab[id][col] f32 = emb(id,:) @ Wx_fused(:,col) + bias_total(col); emb row 0 zeroed.
__global__ __launch_bounds__(256) void build_table(float* __restrict__ tab, const float* __restrict__ emb,
    const float* __restrict__ Wioux, const float* __restrict__ Wfx,
    const float* __restrict__ bioux, const float* __restrict__ biouh1, const float* __restrict__ biouh2,
    const float* __restrict__ bfx, const float* __restrict__ bfh11, const float* __restrict__ bfh12,
    const float* __restrict__ bfh21, const float* __restrict__ bfh22)
{
    __shared__ float As[64][33];
    __shared__ float Ws[32][65];
    const int tid = threadIdx.x, tx = tid & 15, ty = tid >> 4;
    const int i0 = blockIdx.x * 64, c0 = blockIdx.y * 64;
    const int g = c0 >> 8;
    float acc[4][4];
    #pragma unroll
    for (int i = 0; i < 4; ++i)
        #pragma unroll
        for (int j = 0; j < 4; ++j) acc[i][j] = 0.f;

    for (int k0 = 0; k0 < 128; k0 += 32) {
        #pragma unroll
        for (int it = 0; it < 2; ++it) {
            int f = tid + it * 256;
            int row = f >> 3, kk = (f & 7) * 4;
            int gr = i0 + row;
            float4 av = (gr == 0) ? make_float4(0.f, 0.f, 0.f, 0.f)
                                  : *(const float4*)(emb + (size_t)gr * 128 + k0 + kk);
            As[row][kk] = av.x; As[row][kk + 1] = av.y; As[row][kk + 2] = av.z; As[row][kk + 3] = av.w;
            int k = f >> 4, cc = (f & 15) * 4;
            int col = c0 + cc;
            float4 wv = (g < 3) ? *(const float4*)(Wioux + (size_t)(k0 + k) * 768 + col)
                                : *(const float4*)(Wfx + (size_t)(k0 + k) * 256 + (col & 255));
            Ws[k][cc] = wv.x; Ws[k][cc + 1] = wv.y; Ws[k][cc + 2] = wv.z; Ws[k][cc + 3] = wv.w;
        }
        __syncthreads();
        #pragma unroll 8
        for (int k = 0; k < 32; ++k) {
            float a[4], w[4];
            #pragma unroll
            for (int i = 0; i < 4; ++i) a[i] = As[ty * 4 + i][k];
            #pragma unroll
            for (int j = 0; j < 4; ++j) w[j] = Ws[k][tx * 4 + j];
            #pragma unroll
            for (int i = 0; i < 4; ++i)
                #pragma unroll
                for (int j = 0; j < 4; ++j) acc[i][j] = fmaf(a[i], w[j], acc[i][j]);
        }
        __syncthreads();
    }
    #pragma unroll
    for (int j = 0; j < 4; ++j) {
        int col = c0 + tx * 4 + j; int t = col & 255;
        float bs = (g < 3) ? (bioux[col] + biouh1[col] + biouh2[col])
                 : (g == 3) ? (bfx[t] + bfh11[t] + bfh12[t])
                            : (bfx[t] + bfh21[t] + bfh22[t]);
        #pragma unroll
        for (int i = 0; i < 4; ++i)
            tab[(size_t)(i0 + ty * 4 + i) * 1280 + col] = acc[i][j] + bs;
    }
}

// Level-0 result depends only on token id: H0h/H0c[id][t]
__global__ void build_h0c0(const float* __restrict__ tab, _Float16* __restrict__ H0h, float* __restrict__ H0c) {
    int id = blockIdx.x, t = threadIdx.x;
    const float* tp = tab + (size_t)id * 1280 + t;
    float vi = sigm(tp[0]), vo = sigm(tp[256]), vu = tanh_f(tp[512]);
    float c = vi * vu;
    H0h[id * 256 + t] = (_Float16)(vo * tanh_f(c));
    H0c[id * 256 + t] = c;
}

// Tree-level cell v5: barrier-free K-loop.
// Block = 4 waves x (RT*16) rows x 16 t-cols x 5 gates. K=512 in two phases of 256.
// B slice (80 n-rows x 256 k, 40KB) staged ONCE per phase, XOR-swizzled (slot j^(n&7)),
// phase-1 via pre-swizzled global_load_lds source; phase-2 prefetched to regs at start
// (T14) and ds_written after one barrier. K-steps have NO barriers.
// A: direct per-lane global loads in fragment layout, depth-1 register prefetch.
template<bool LVL1, int RT>
__global__ __launch_bounds__(256, 2) void cell5(
    const _Float16* __restrict__ WTh, const float* __restrict__ tab,
    const int* __restrict__ ids,
    const _Float16* __restrict__ h_prev, const float* __restrict__ c_prev,
    _Float16* __restrict__ h_out, float* __restrict__ c_out,
    int n, int ln, int off)
{
    constexpr int BM = RT * 64;
    __shared__ _Float16 Bs[80 * 256];          // 40 KB
    const int tid = threadIdx.x, lane = tid & 63, wid = tid >> 6;
    const int l15 = lane & 15, lg = lane >> 4;
    const int rowB = blockIdx.x * BM;
    const int t0 = blockIdx.y * 16;

    // ---- A source pointers per row-frag (k<256 -> aPA, k>=256 -> aPB)
    const _Float16* aPA[RT];
    const _Float16* aPB[RT];
    #pragma unroll
    for (int rt = 0; rt < RT; ++rt) {
        int row = rowB + wid * (RT * 16) + rt * 16 + l15;
        if constexpr (LVL1) {
            int b = row >> 7, j = row & 127;
            aPA[rt] = h_prev + (size_t)ids[b * NODES_ + 2 * j] * 256 + lg * 8;
            aPB[rt] = h_prev + (size_t)ids[b * NODES_ + 2 * j + 1] * 256 + lg * 8;
        } else {
            aPA[rt] = h_prev + (size_t)row * 512 + lg * 8;
            aPB[rt] = aPA[rt] + 256;
        }
    }

    // ---- B staging: 2560 slots of 16B; thread owns slots tid + i*256.
    // LDS slot (n*32+j) holds global seg j^(n&7) of staged row n (n = g*16+tl).
    const _Float16* sp[10];
    #pragma unroll
    for (int i = 0; i < 10; ++i) {
        int slot = tid + i * 256;
        int nr = slot >> 5, j = slot & 31;
        int g = nr >> 4, tl = nr & 15;
        sp[i] = WTh + (size_t)(g * 256 + t0 + tl) * 512 + ((j ^ (nr & 7)) * 8);
    }
    #pragma unroll
    for (int i = 0; i < 10; ++i)
        gload16(sp[i], &Bs[(size_t)(tid + i * 256) * 8]);
    // phase-2 B prefetch to registers (rides under phase-1 compute)
    half8 breg[10];
    #pragma unroll
    for (int i = 0; i < 10; ++i) breg[i] = *(const half8*)(sp[i] + 256);

    half8 aF[2][RT];
    #pragma unroll
    for (int rt = 0; rt < RT; ++rt) aF[0][rt] = *(const half8*)(aPA[rt]);

    f32x4 acc[RT][5];
    #pragma unroll
    for (int rt = 0; rt < RT; ++rt)
        #pragma unroll
        for (int g = 0; g < 5; ++g) acc[rt][g] = (f32x4)0.f;

    __syncthreads();                            // phase-1 B staged

    // ---- phase 1: k in [0,256), 8 steps, NO barriers
    #pragma unroll
    for (int s = 0; s < 8; ++s) {
        const int cur = s & 1, nxt = cur ^ 1;
        #pragma unroll
        for (int rt = 0; rt < RT; ++rt)
            aF[nxt][rt] = (s < 7) ? *(const half8*)(aPA[rt] + (s + 1) * 32)
                                  : *(const half8*)(aPB[rt]);
        #pragma unroll
        for (int g = 0; g < 5; ++g) {
            int nr = g * 16 + l15;
            int j = (s * 4 + lg) ^ (nr & 7);
            half8 bF = *(const half8*)&Bs[(size_t)(nr * 32 + j) * 8];
            #pragma unroll
            for (int rt = 0; rt < RT; ++rt)
                acc[rt][g] = __builtin_amdgcn_mfma_f32_16x16x32_f16(aF[cur][rt], bF, acc[rt][g], 0, 0, 0);
        }
    }

    __syncthreads();                            // all phase-1 reads done
    #pragma unroll
    for (int i = 0; i < 10; ++i)
        *(half8*)&Bs[(size_t)(tid + i * 256) * 8] = breg[i];
    __syncthreads();                            // phase-2 B staged

    // ---- phase 2: k in [256,512), 8 steps, NO barriers
    #pragma unroll
    for (int s = 0; s < 8; ++s) {
        const int cur = s & 1, nxt = cur ^ 1;
        if (s < 7) {
            #pragma unroll
            for (int rt = 0; rt < RT; ++rt)
                aF[nxt][rt] = *(const half8*)(aPB[rt] + (s + 1) * 32);
        }
        #pragma unroll
        for (int g = 0; g < 5; ++g) {
            int nr = g * 16 + l15;
            int j = (s * 4 + lg) ^ (nr & 7);
            half8 bF = *(const half8*)&Bs[(size_t)(nr * 32 + j) * 8];
            #pragma unroll
            for (int rt = 0; rt < RT; ++rt)
                acc[rt][g] = __builtin_amdgcn_mfma_f32_16x16x32_f16(aF[cur][rt], bF, acc[rt][g], 0, 0, 0);
        }
    }

    // ---- fused epilogue. D: col = lane&15, row = (lane>>4)*4 + q
    const int tcol = t0 + l15;
    #pragma unroll
    for (int rt = 0; rt < RT; ++rt) {
        #pragma unroll
        for (int q = 0; q < 4; ++q) {
            int row = rowB + wid * (RT * 16) + rt * 16 + lg * 4 + q;
            int b = row >> ln, j = row & (n - 1);
            int id = ids[b * NODES_ + off + j];
            const float* tp = tab + (size_t)id * 1280 + tcol;
            float c1, c2;
            if constexpr (LVL1) {
                int bb = row >> 7, jj = row & 127;
                c1 = c_prev[(size_t)ids[bb * NODES_ + 2 * jj] * 256 + tcol];
                c2 = c_prev[(size_t)ids[bb * NODES_ + 2 * jj + 1] * 256 + tcol];
            } else {
                const float* cpp = c_prev + (size_t)row * 512 + tcol;
                c1 = cpp[0]; c2 = cpp[256];
            }
            float vi  = sigm(acc[rt][0][q] + tp[0]);
            float vo  = sigm(acc[rt][1][q] + tp[256]);
            float vu  = tanh_f(acc[rt][2][q] + tp[512]);
            float vf0 = sigm(acc[rt][3][q] + tp[768]);
            float vf1 = sigm(acc[rt][4][q] + tp[1024]);
            float c = vi * vu + vf0 * c1 + vf1 * c2;
            size_t ob = (size_t)row * 256 + tcol;
            h_out[ob] = (_Float16)(vo * tanh_f(c));
            c_out[ob] = c;
        }
    }
}

// pred[b] = relu(h_root[b] @ Wl1 + bl1) @ Wl2 + bl2
__global__ void head_kernel(const _Float16* __restrict__ hroot,
    const float* __restrict__ Wl1, const float* __restrict__ bl1,
    const float* __restrict__ Wl2, const float* __restrict__ bl2,
    float* __restrict__ out)
{
    __shared__ float hrow[H_];
    __shared__ float red[256];
    int b = blockIdx.x; int tid = threadIdx.x;
    hrow[tid] = (float)hroot[(size_t)b * H_ + tid];
    __syncthreads();
    float v = 0.f;
    if (tid < 100) {
        float s = bl1[tid];
        for (int k = 0; k < H_; ++k) s = fmaf(hrow[k], Wl1[k * 100 + tid], s);
        v = fmaxf(s, 0.f) * Wl2[tid];
    }
    red[tid] = v;
    __syncthreads();
    for (int s = 128; s > 0; s >>= 1) { if (tid < s) red[tid] += red[tid + s]; __syncthreads(); }
    if (tid == 0) out[b] = red[0] + bl2[0];
}

extern "C" void kernel_launch(void* const* d_in, const int* in_sizes, int n_in,
                              void* d_out, int out_size, void* d_ws, size_t ws_size,
                              hipStream_t stream) {
    const int*   ids    = (const int*)d_in[0];
    const float* emb    = (const float*)d_in[1];
    const float* Wioux  = (const float*)d_in[2];
    const float* bioux  = (const float*)d_in[3];
    const float* Wiouh1 = (const float*)d_in[4];
    const float* biouh1 = (const float*)d_in[5];
    const float* Wiouh2 = (const float*)d_in[6];
    const float* biouh2 = (const float*)d_in[7];
    const float* Wfx    = (const float*)d_in[8];
    const float* bfx    = (const float*)d_in[9];
    const float* Wfh11  = (const float*)d_in[10];
    const float* bfh11  = (const float*)d_in[11];
    const float* Wfh12  = (const float*)d_in[12];
    const float* bfh12  = (const float*)d_in[13];
    const float* Wfh21  = (const float*)d_in[14];
    const float* bfh21  = (const float*)d_in[15];
    const float* Wfh22  = (const float*)d_in[16];
    const float* bfh22  = (const float*)d_in[17];
    const float* Wl1    = (const float*)d_in[18];
    const float* bl1    = (const float*)d_in[19];
    const float* Wl2    = (const float*)d_in[20];
    const float* bl2    = (const float*)d_in[21];
    float* out = (float*)d_out;

    // ws layout (bytes)
    char* wsb = (char*)d_ws;
    _Float16* WTh = (_Float16*)(wsb);                    //  1,310,720
    float*    tab = (float*)(wsb + 1310720);             // 10,485,760
    _Float16* H0h = (_Float16*)(wsb + 11796480);         //  1,048,576
    float*    H0c = (float*)(wsb + 12845056);            //  2,097,152
    _Float16* hA  = (_Float16*)(wsb + 14942208);         //  8,388,608  (lvl 2,4,6,8 out)
    _Float16* hB  = (_Float16*)(wsb + 23330816);         // 16,777,216  (lvl 1,3,5,7 out)
    float*    cA  = (float*)(wsb + 40108032);            // 16,777,216
    float*    cB  = (float*)(wsb + 56885248);            // 33,554,432  -> ends 90,439,680

    build_WTh<<<dim3(2560), 256, 0, stream>>>(WTh, Wiouh1, Wfh11, Wfh21, Wiouh2, Wfh12, Wfh22);
    build_table<<<dim3(32, 20), 256, 0, stream>>>(tab, emb, Wioux, Wfx,
        bioux, biouh1, biouh2, bfx, bfh11, bfh12, bfh21, bfh22);
    build_h0c0<<<dim3(2048), 256, 0, stream>>>(tab, H0h, H0c);

    // level 1: A gathered from id-indexed H0 tables
    cell5<true, 4><<<dim3(128, 16), 256, 0, stream>>>(WTh, tab, ids, H0h, H0c, hB, cB, 128, 7, 256);

    _Float16 *hp = hB, *hn = hA;
    float    *cp = cB, *cn = cA;
    int off = 384, n = 64, ln = 6;
    for (int lvl = 2; lvl <= 8; ++lvl) {
        int M = B_ * n;
        if (M >= 4096)
            cell5<false, 4><<<dim3(M / 256, 16), 256, 0, stream>>>(WTh, tab, ids, hp, cp, hn, cn, n, ln, off);
        else
            cell5<false, 1><<<dim3(M / 64, 16), 256, 0, stream>>>(WTh, tab, ids, hp, cp, hn, cn, n, ln, off);
        off += n; n >>= 1; --ln;
        _Float16* t1 = hp; hp = hn; hn = t1;
        float*    t2 = cp; cp = cn; cn = t2;
    }

    head_kernel<<<dim3(256), 256, 0, stream>>>(hp, Wl1, bl1, Wl2, bl2, out);
}